// Round 7
// baseline (73.540 us; speedup 1.0000x reference)
//
#include <hip/hip_runtime.h>

typedef _Float16 half8 __attribute__((ext_vector_type(8)));
typedef float f32x4 __attribute__((ext_vector_type(4)));

#define HH 96
#define WW 96
#define NN (HH * WW)        // 9216
#define T16 (NN / 16)       // 576 16-pixel tiles
#define AG (T16 / 4)        // 144 a-groups (4 a-tiles per block)
#define NDC 37              // dc 0..35: d=1..288 (8 d's each); dc 36: diagonal d=0
#define NPART (AG * NDC)    // 5328 block partials

// Gaussian constants with log2(e) folded in (native v_exp_f32 is exp2):
// CXY = log2(e)/(2*15^2), CRGB = log2(e)/(2*0.125^2)
#define CXY 0.0032059890f
#define CRGB 46.16624131f

// arg_ij is computed as a K=32 f16 MFMA dot:
//   u(i) = [uh(5), uh(5), ul(5), Aih, Ail, 1, 1, 0...]   (uh/ul = f16 hi/lo split)
//   v(j) = [vh(5), vl(5), vh(5), 1, 1, Ajh, Ajl, 0...]   (v = 2C-scaled values)
//   u.v  = Σ uh*vh + uh*vl + ul*vh + Ai + Aj  (drops ul*vl ~1e-5 — negligible)
// Storage is fragment-interleaved per tile: uint4 index = tile*64 + kquad*16 + pixel_in_tile,
// so A/B fragment loads and LDS reads are linear & conflict-free.
// Symmetric pair coverage (cyclic offsets): d=0 diag w=1; d=1..287 all a, w=2;
// d=288 only a<288, w=2. Total effective ordered pairs = 576^2. Verified sum:
// 576 + 2*576*287 + 2*288 = 331776.

__global__ __launch_bounds__(256) void crf_prep(
    const float* __restrict__ probs,   // [2,N] class-0 first
    const float* __restrict__ image,   // [3,N]
    uint4* __restrict__ ug, uint4* __restrict__ vg)
{
    const int p = blockIdx.x * 256 + threadIdx.x;   // 36 blocks, exactly NN threads
    const int y = p / WW, x = p - y * WW;
    const float fy = (float)y, fx = (float)x;
    const float r = image[p], g = image[NN + p], b = image[2 * NN + p];
    const float Ai = -CXY * fmaf(fy, fy, fx * fx)
                     - CRGB * fmaf(r, r, fmaf(g, g, b * b));
    const float uv[5] = {fy, fx, r, g, b};
    const float vv[5] = {2.0f * CXY * fy, 2.0f * CXY * fx,
                         2.0f * CRGB * r, 2.0f * CRGB * g, 2.0f * CRGB * b};
    union { _Float16 h[32]; uint4 q[4]; } U, V;
#pragma unroll
    for (int k = 0; k < 32; ++k) { U.h[k] = (_Float16)0.0f; V.h[k] = (_Float16)0.0f; }
#pragma unroll
    for (int d = 0; d < 5; ++d) {
        const _Float16 uh = (_Float16)uv[d];
        const _Float16 ul = (_Float16)(uv[d] - (float)uh);
        const _Float16 vh = (_Float16)vv[d];
        const _Float16 vl = (_Float16)(vv[d] - (float)vh);
        U.h[d] = uh; U.h[5 + d] = uh; U.h[10 + d] = ul;
        V.h[d] = vh; V.h[5 + d] = vl; V.h[10 + d] = vh;
    }
    const _Float16 Ah = (_Float16)Ai;
    const _Float16 Al = (_Float16)(Ai - (float)Ah);
    U.h[15] = Ah; U.h[16] = Al; U.h[17] = (_Float16)1.0f; U.h[18] = (_Float16)1.0f;
    V.h[15] = (_Float16)1.0f; V.h[16] = (_Float16)1.0f; V.h[17] = Ah; V.h[18] = Al;

    const int tile = p >> 4, pl = p & 15;
#pragma unroll
    for (int q = 0; q < 4; ++q) {
        ug[tile * 64 + q * 16 + pl] = U.q[q];
        vg[tile * 64 + q * 16 + pl] = V.q[q];
    }
}

__global__ __launch_bounds__(256) void crf_mfma_kernel(
    const uint4* __restrict__ ug, const uint4* __restrict__ vg,
    const float* __restrict__ probs,
    float* __restrict__ partials)
{
    __shared__ uint4 sv[11 * 64];   // 11-tile v-window, fragment-interleaved (11 KB)
    __shared__ float sa[11 * 16];   // probs for the window
    __shared__ float wsum[4];

    const int g = blockIdx.x, dc = blockIdx.y;
    const int tid = threadIdx.x, lane = tid & 63, wave = tid >> 6;
    const bool diag = (dc == 36);

    int win0 = diag ? g * 4 : (g * 4 + 1 + dc * 8);
    if (win0 >= T16) win0 -= T16;

    // Stage the 11-tile v-window + probs window into LDS (coalesced, linear).
    for (int t = tid; t < 11 * 64; t += 256) {
        int tile = win0 + (t >> 6); if (tile >= T16) tile -= T16;
        sv[t] = vg[tile * 64 + (t & 63)];
    }
    if (tid < 11 * 16) {
        int tile = win0 + (tid >> 4); if (tile >= T16) tile -= T16;
        sa[tid] = probs[tile * 16 + (tid & 15)];
    }

    // Wave prologue: own a-tile, A-fragment, row probs (overlaps staging).
    const int a_tile = g * 4 + wave;
    const int quad = lane >> 4, col = lane & 15;
    union { uint4 q; half8 h; } A;
    A.q = ug[a_tile * 64 + quad * 16 + col];
    const float4 aiv = *(const float4*)(probs + a_tile * 16 + quad * 4);
    const float ww = diag ? 1.0f : 2.0f;
    float wai[4], wci[4];
    const float aiarr[4] = {aiv.x, aiv.y, aiv.z, aiv.w};
#pragma unroll
    for (int r2 = 0; r2 < 4; ++r2) {
        wai[r2] = ww * aiarr[r2];
        wci[r2] = ww * fmaf(-2.0f, aiarr[r2], 1.0f);   // w*(1-2ai)
    }
    int nu = diag ? 1 : 8;
    if (dc == 35 && a_tile >= 288) nu = 7;   // drop d=288 for a>=288 (pair counted once)

    f32x4 acc; acc[0] = 0.0f; acc[1] = 0.0f; acc[2] = 0.0f; acc[3] = 0.0f;
    __syncthreads();

    for (int s = 0; s < nu; ++s) {
        const int bl = wave + s;                    // b_local in 0..10
        union { uint4 q; half8 h; } B;
        B.q = sv[bl * 64 + quad * 16 + col];        // conflict-free ds_read_b128
        f32x4 c0; c0[0] = 0.0f; c0[1] = 0.0f; c0[2] = 0.0f; c0[3] = 0.0f;
        const f32x4 dd = __builtin_amdgcn_mfma_f32_16x16x32_f16(A.h, B.h, c0, 0, 0, 0);
        const float aj = sa[bl * 16 + col];         // broadcast read
#pragma unroll
        for (int r2 = 0; r2 < 4; ++r2) {
            const float K = __builtin_amdgcn_exp2f(dd[r2]);
            const float wv = fmaf(aj, wci[r2], wai[r2]);   // w*(ai + aj*(1-2ai))
            acc[r2] = fmaf(wv, K, acc[r2]);
        }
    }

    // Reduce: lane -> wave -> block partial (no atomics; R4: single-address RMWs serialize).
    float s4 = (acc[0] + acc[1]) + (acc[2] + acc[3]);
    for (int off = 32; off > 0; off >>= 1)
        s4 += __shfl_down(s4, off, 64);
    if (lane == 0) wsum[wave] = s4;
    __syncthreads();
    if (tid == 0)
        partials[blockIdx.y * AG + blockIdx.x] =
            (wsum[0] + wsum[1]) + (wsum[2] + wsum[3]);
}

__global__ __launch_bounds__(256) void crf_finalize_kernel(
    const float* __restrict__ partials, float* __restrict__ out)
{
    const int tid = threadIdx.x;
    float s = 0.0f;
    for (int t = tid; t < NPART; t += 256)
        s += partials[t];
    for (int off = 32; off > 0; off >>= 1)
        s += __shfl_down(s, off, 64);
    __shared__ float wsum[4];
    if ((tid & 63) == 0) wsum[tid >> 6] = s;
    __syncthreads();
    if (tid == 0)
        out[0] = ((wsum[0] + wsum[1]) + (wsum[2] + wsum[3])) * (1.0f / (float)NN);
}

extern "C" void kernel_launch(void* const* d_in, const int* in_sizes, int n_in,
                              void* d_out, int out_size, void* d_ws, size_t ws_size,
                              hipStream_t stream) {
    const float* probs = (const float*)d_in[0];  // [1,2,96,96] fp32
    const float* image = (const float*)d_in[1];  // [1,3,96,96] fp32
    float* out = (float*)d_out;                  // [1] fp32

    // Workspace layout (re-poisoned every call; everything recomputed below):
    uint4* ug = (uint4*)d_ws;                                   // 9216*64 B
    uint4* vg = (uint4*)((char*)d_ws + NN * 64);                // 9216*64 B
    float* partials = (float*)((char*)d_ws + 2 * NN * 64);      // 5328 floats

    crf_prep<<<dim3(NN / 256), dim3(256), 0, stream>>>(probs, image, ug, vg);
    crf_mfma_kernel<<<dim3(AG, NDC), dim3(256), 0, stream>>>(ug, vg, probs, partials);
    crf_finalize_kernel<<<dim3(1), dim3(256), 0, stream>>>(partials, out);
}

// Round 8
// 67.677 us; speedup vs baseline: 1.0866x; 1.0866x over previous
//
#include <hip/hip_runtime.h>

typedef _Float16 half8 __attribute__((ext_vector_type(8)));
typedef float f32x4 __attribute__((ext_vector_type(4)));

#define HH 96
#define WW 96
#define NN (HH * WW)        // 9216
#define T16 (NN / 16)       // 576 16-pixel tiles
#define AG (T16 / 4)        // 144 a-groups (4 a-tiles per block, one per wave)
#define NDC 9               // d-chunks: dc covers d = dc*32+1 .. dc*32+32 (+ d=0 peeled on dc=0)
#define WIN 36              // window tiles per block (b_local = wave + 1 + s, max 35)
#define NPART (AG * NDC)    // 1296 block partials

// Gaussian constants with log2(e) folded in (native v_exp_f32 is exp2):
#define CXY 0.0032059890f
#define CRGB 46.16624131f

// arg_ij as a K=32 f16 MFMA dot (layout verified absmax-0.0 in R7):
//   U = [uh(5), uh(5), ul(5), Aih, Ail, 1, 1, 0..]   (uh/ul = f16 hi/lo split)
//   V = [vh(5), vl(5), vh(5), 1, 1, Ajh, Ajl, 0..]   (v = 2C-scaled values)
//   U.V = (u.v) - ul.vl + Ai + Aj ≈ arg  (dropped ul*vl ~1e-5)
// Fragment-interleaved LDS: sv[tile*64 + kquad*16 + pixel] (uint4).
// Symmetric coverage via cyclic offsets: d=0 w=1 (peeled, dc==0); d=1..287 w=2;
// d=288 w=1 for ALL a (each unordered pair hit twice). 576*(1+2*287+1)=576^2. ✓
// No single-address atomics (R4: ~14.5 ns serialized RMW each). Two dispatches.

__device__ __forceinline__ void pix_data(
    const float* __restrict__ image, const float* __restrict__ probs, int p,
    float& fy, float& fx, float& r, float& g, float& b, float& A, float& a)
{
    const int y = p / WW;
    fy = (float)y; fx = (float)(p - y * WW);
    r = image[p]; g = image[NN + p]; b = image[2 * NN + p]; a = probs[p];
    A = -CXY * fmaf(fy, fy, fx * fx) - CRGB * fmaf(r, r, fmaf(g, g, b * b));
}

__global__ __launch_bounds__(256) void crf_mfma2(
    const float* __restrict__ probs, const float* __restrict__ image,
    float* __restrict__ partials)
{
    __shared__ uint4 sv[WIN * 64];   // 36 KB: V fragments for the window
    __shared__ float sa[WIN * 16];   // aj for the window
    __shared__ float wsum[4];

    const int g = blockIdx.x, dc = blockIdx.y;
    const int tid = threadIdx.x, lane = tid & 63, wave = tid >> 6;
    const int quad = lane >> 4, col = lane & 15;
    const int wb = g * 4 + dc * 32;   // window base tile (mod T16)

    // ---- Stage window: compute V fragments straight into LDS (prep fused). ----
    for (int t = tid; t < WIN * 16; t += 256) {
        int tile = wb + (t >> 4); if (tile >= T16) tile -= T16;
        const int j = tile * 16 + (t & 15);
        float fy, fx, r, gg, b, Aj, aj;
        pix_data(image, probs, j, fy, fx, r, gg, b, Aj, aj);
        const float vv[5] = {2.0f * CXY * fy, 2.0f * CXY * fx,
                             2.0f * CRGB * r, 2.0f * CRGB * gg, 2.0f * CRGB * b};
        union { _Float16 h[32]; uint4 q[4]; } V;
#pragma unroll
        for (int k = 0; k < 32; ++k) V.h[k] = (_Float16)0.0f;
#pragma unroll
        for (int d = 0; d < 5; ++d) {
            const _Float16 vh = (_Float16)vv[d];
            const _Float16 vl = (_Float16)(vv[d] - (float)vh);
            V.h[d] = vh; V.h[5 + d] = vl; V.h[10 + d] = vh;
        }
        const _Float16 Ah = (_Float16)Aj, Al = (_Float16)(Aj - (float)Ah);
        V.h[15] = (_Float16)1.0f; V.h[16] = (_Float16)1.0f; V.h[17] = Ah; V.h[18] = Al;
#pragma unroll
        for (int q = 0; q < 4; ++q) sv[(t >> 4) * 64 + q * 16 + (t & 15)] = V.q[q];
        sa[t] = aj;
    }

    // ---- Per-wave prologue (register-only, overlaps staging): A fragment. ----
    const int a_tile = g * 4 + wave;          // < 576 always
    const int ip = a_tile * 16 + col;
    float fy, fx, r, gg, b, Ai, dum;
    pix_data(image, probs, ip, fy, fx, r, gg, b, Ai, dum);
    union { _Float16 h[8]; half8 v; } A;
#pragma unroll
    for (int k = 0; k < 8; ++k) A.h[k] = (_Float16)0.0f;
    {
        const float uv[5] = {fy, fx, r, gg, b};
        _Float16 uh[5], ul[5];
#pragma unroll
        for (int d = 0; d < 5; ++d) {
            uh[d] = (_Float16)uv[d];
            ul[d] = (_Float16)(uv[d] - (float)uh[d]);
        }
        const _Float16 Ah = (_Float16)Ai, Al = (_Float16)(Ai - (float)Ah);
        if (quad == 0) {
            A.h[0] = uh[0]; A.h[1] = uh[1]; A.h[2] = uh[2]; A.h[3] = uh[3];
            A.h[4] = uh[4]; A.h[5] = uh[0]; A.h[6] = uh[1]; A.h[7] = uh[2];
        } else if (quad == 1) {
            A.h[0] = uh[3]; A.h[1] = uh[4]; A.h[2] = ul[0]; A.h[3] = ul[1];
            A.h[4] = ul[2]; A.h[5] = ul[3]; A.h[6] = ul[4]; A.h[7] = Ah;
        } else if (quad == 2) {
            A.h[0] = Al; A.h[1] = (_Float16)1.0f; A.h[2] = (_Float16)1.0f;
        } // quad 3: all zero
    }
    // Epilogue row data: rows r2 -> i = a_tile*16 + quad*4 + r2 (R7-verified C/D map).
    const float4 aiv = *(const float4*)(probs + a_tile * 16 + quad * 4);
    const float air[4] = {aiv.x, aiv.y, aiv.z, aiv.w};
    float cir[4];
#pragma unroll
    for (int r2 = 0; r2 < 4; ++r2) cir[r2] = fmaf(-2.0f, air[r2], 1.0f);

    f32x4 acc2 = {0.0f, 0.0f, 0.0f, 0.0f};   // weight-2 part
    f32x4 acc1 = {0.0f, 0.0f, 0.0f, 0.0f};   // weight-1 part (d=0, d=288)
    __syncthreads();

    const int nmain = (dc == NDC - 1) ? 31 : 32;   // dc=8 peels d=288
    for (int s = 0; s < nmain; ++s) {
        const int bl = wave + 1 + s;              // 1..35
        union { uint4 q; half8 h; } B;
        B.q = sv[bl * 64 + quad * 16 + col];
        f32x4 c0 = {0.0f, 0.0f, 0.0f, 0.0f};
        const f32x4 dd = __builtin_amdgcn_mfma_f32_16x16x32_f16(A.v, B.h, c0, 0, 0, 0);
        const float aj = sa[bl * 16 + col];
#pragma unroll
        for (int r2 = 0; r2 < 4; ++r2) {
            const float K = __builtin_amdgcn_exp2f(dd[r2]);
            const float wv = fmaf(aj, cir[r2], air[r2]);   // ai + aj*(1-2ai)
            acc2[r2] = fmaf(wv, K, acc2[r2]);
        }
    }
    // Peeled weight-1 iterations (block-uniform branches).
    if (dc == NDC - 1 || dc == 0) {
        const int bl = (dc == 0) ? wave : wave + 32;   // d=0 diag / d=288
        union { uint4 q; half8 h; } B;
        B.q = sv[bl * 64 + quad * 16 + col];
        f32x4 c0 = {0.0f, 0.0f, 0.0f, 0.0f};
        const f32x4 dd = __builtin_amdgcn_mfma_f32_16x16x32_f16(A.v, B.h, c0, 0, 0, 0);
        const float aj = sa[bl * 16 + col];
#pragma unroll
        for (int r2 = 0; r2 < 4; ++r2) {
            const float K = __builtin_amdgcn_exp2f(dd[r2]);
            const float wv = fmaf(aj, cir[r2], air[r2]);
            acc1[r2] = fmaf(wv, K, acc1[r2]);
        }
    }

    // Reduce: lane -> wave -> block partial.
    float s4 = 2.0f * ((acc2[0] + acc2[1]) + (acc2[2] + acc2[3]))
             + ((acc1[0] + acc1[1]) + (acc1[2] + acc1[3]));
    for (int off = 32; off > 0; off >>= 1)
        s4 += __shfl_down(s4, off, 64);
    if (lane == 0) wsum[wave] = s4;
    __syncthreads();
    if (tid == 0)
        partials[dc * AG + g] = (wsum[0] + wsum[1]) + (wsum[2] + wsum[3]);
}

__global__ __launch_bounds__(256) void crf_finalize_kernel(
    const float* __restrict__ partials, float* __restrict__ out)
{
    const int tid = threadIdx.x;
    float s = 0.0f;
    for (int t = tid; t < NPART; t += 256)
        s += partials[t];
    for (int off = 32; off > 0; off >>= 1)
        s += __shfl_down(s, off, 64);
    __shared__ float wsum[4];
    if ((tid & 63) == 0) wsum[tid >> 6] = s;
    __syncthreads();
    if (tid == 0)
        out[0] = ((wsum[0] + wsum[1]) + (wsum[2] + wsum[3])) * (1.0f / (float)NN);
}

extern "C" void kernel_launch(void* const* d_in, const int* in_sizes, int n_in,
                              void* d_out, int out_size, void* d_ws, size_t ws_size,
                              hipStream_t stream) {
    const float* probs = (const float*)d_in[0];  // [1,2,96,96] fp32
    const float* image = (const float*)d_in[1];  // [1,3,96,96] fp32
    float* out = (float*)d_out;                  // [1] fp32
    float* partials = (float*)d_ws;              // NPART floats

    crf_mfma2<<<dim3(AG, NDC), dim3(256), 0, stream>>>(probs, image, partials);
    crf_finalize_kernel<<<dim3(1), dim3(256), 0, stream>>>(partials, out);
}

// Round 9
// 65.110 us; speedup vs baseline: 1.1295x; 1.0394x over previous
//
#include <hip/hip_runtime.h>

typedef _Float16 half8 __attribute__((ext_vector_type(8)));
typedef float f32x4 __attribute__((ext_vector_type(4)));

#define HH 96
#define WW 96
#define NN (HH * WW)        // 9216
#define T16 (NN / 16)       // 576 16-pixel tiles
#define BLK 512
#define AG (T16 / 8)        // 72 a-groups (8 a-tiles per block, one per wave)
#define NDC 9               // d-chunks: dc covers d = dc*32+1 .. dc*32+32 (+peels)
#define WIN 40              // window tiles: b_local = wave(0..7) + 1 + s(0..31) <= 39
#define NPART (AG * NDC)    // 648 block partials

// Gaussian constants with log2(e) folded in (native v_exp_f32 is exp2):
#define CXY 0.0032059890f
#define CRGB 46.16624131f

// arg_ij as a K=32 f16 MFMA dot (layout verified absmax-0.0 in R7/R8):
//   U = [uh(5), uh(5), ul(5), Aih, Ail, 1, 1, 0..]   (uh/ul = f16 hi/lo split)
//   V = [vh(5), vl(5), vh(5), 1, 1, Ajh, Ajl, 0..]   (v = 2C-scaled values)
// Epilogue restructure (R9): sum w*K = ai*R + (1-2ai)*Q with R=Σw_d K, Q=Σw_d aj K
// -> per s per row: 1 exp + 1 add + 1 fma (was 1 exp + 2 fma).
// Symmetric coverage: d=0 w=1 (peeled, dc==0); d=1..287 w=2; d=288 w=1 for ALL a
// (each unordered pair hit twice). 576*(1+2*287+1)=576^2. Verified R8 absmax 0.0.
// No single-address atomics (R4: serialized RMW). Two dispatches.

__device__ __forceinline__ void pix_data(
    const float* __restrict__ image, const float* __restrict__ probs, int p,
    float& fy, float& fx, float& r, float& g, float& b, float& A, float& a)
{
    const int y = p / WW;
    fy = (float)y; fx = (float)(p - y * WW);
    r = image[p]; g = image[NN + p]; b = image[2 * NN + p]; a = probs[p];
    A = -CXY * fmaf(fy, fy, fx * fx) - CRGB * fmaf(r, r, fmaf(g, g, b * b));
}

__global__ __launch_bounds__(BLK, 6) void crf_mfma3(
    const float* __restrict__ probs, const float* __restrict__ image,
    float* __restrict__ partials)
{
    __shared__ uint4 sv[WIN * 64];   // 40 KB: V fragments for the window
    __shared__ float sa[WIN * 16];   // aj for the window
    __shared__ float wsum[8];

    const int g = blockIdx.x, dc = blockIdx.y;
    const int tid = threadIdx.x, lane = tid & 63, wave = tid >> 6;
    const int quad = lane >> 4, col = lane & 15;
    const int wb = g * 8 + dc * 32;   // window base tile (mod T16)

    // ---- Stage window: compute V fragments straight into LDS. ----
    for (int t = tid; t < WIN * 16; t += BLK) {
        int tile = wb + (t >> 4); if (tile >= T16) tile -= T16;
        const int j = tile * 16 + (t & 15);
        float fy, fx, r, gg, b, Aj, aj;
        pix_data(image, probs, j, fy, fx, r, gg, b, Aj, aj);
        const float vv[5] = {2.0f * CXY * fy, 2.0f * CXY * fx,
                             2.0f * CRGB * r, 2.0f * CRGB * gg, 2.0f * CRGB * b};
        union { _Float16 h[32]; uint4 q[4]; } V;
#pragma unroll
        for (int k = 0; k < 32; ++k) V.h[k] = (_Float16)0.0f;
#pragma unroll
        for (int d = 0; d < 5; ++d) {
            const _Float16 vh = (_Float16)vv[d];
            const _Float16 vl = (_Float16)(vv[d] - (float)vh);
            V.h[d] = vh; V.h[5 + d] = vl; V.h[10 + d] = vh;
        }
        const _Float16 Ah = (_Float16)Aj, Al = (_Float16)(Aj - (float)Ah);
        V.h[15] = (_Float16)1.0f; V.h[16] = (_Float16)1.0f; V.h[17] = Ah; V.h[18] = Al;
#pragma unroll
        for (int q = 0; q < 4; ++q) sv[(t >> 4) * 64 + q * 16 + (t & 15)] = V.q[q];
        sa[t] = aj;
    }

    // ---- Per-wave prologue (register-only, overlaps staging): A fragment. ----
    const int a_tile = g * 8 + wave;          // < 576 always
    const int ip = a_tile * 16 + col;
    float fy, fx, r, gg, b, Ai, dum;
    pix_data(image, probs, ip, fy, fx, r, gg, b, Ai, dum);
    union { _Float16 h[8]; half8 v; } A;
#pragma unroll
    for (int k = 0; k < 8; ++k) A.h[k] = (_Float16)0.0f;
    {
        const float uv[5] = {fy, fx, r, gg, b};
        _Float16 uh[5], ul[5];
#pragma unroll
        for (int d = 0; d < 5; ++d) {
            uh[d] = (_Float16)uv[d];
            ul[d] = (_Float16)(uv[d] - (float)uh[d]);
        }
        const _Float16 Ah = (_Float16)Ai, Al = (_Float16)(Ai - (float)Ah);
        if (quad == 0) {
            A.h[0] = uh[0]; A.h[1] = uh[1]; A.h[2] = uh[2]; A.h[3] = uh[3];
            A.h[4] = uh[4]; A.h[5] = uh[0]; A.h[6] = uh[1]; A.h[7] = uh[2];
        } else if (quad == 1) {
            A.h[0] = uh[3]; A.h[1] = uh[4]; A.h[2] = ul[0]; A.h[3] = ul[1];
            A.h[4] = ul[2]; A.h[5] = ul[3]; A.h[6] = ul[4]; A.h[7] = Ah;
        } else if (quad == 2) {
            A.h[0] = Al; A.h[1] = (_Float16)1.0f; A.h[2] = (_Float16)1.0f;
        } // quad 3: all zero
    }
    // Epilogue row data: rows r2 -> i = a_tile*16 + quad*4 + r2 (verified C/D map).
    const float4 aiv = *(const float4*)(probs + a_tile * 16 + quad * 4);
    const float air[4] = {aiv.x, aiv.y, aiv.z, aiv.w};

    f32x4 R2 = {0.0f, 0.0f, 0.0f, 0.0f}, Q2 = {0.0f, 0.0f, 0.0f, 0.0f};  // w=2
    f32x4 R1 = {0.0f, 0.0f, 0.0f, 0.0f}, Q1 = {0.0f, 0.0f, 0.0f, 0.0f};  // w=1
    __syncthreads();

    const int nmain = (dc == NDC - 1) ? 31 : 32;   // dc=8 peels d=288
#pragma unroll 2
    for (int s = 0; s < nmain; ++s) {
        const int bl = wave + 1 + s;              // 1..39
        union { uint4 q; half8 h; } B;
        B.q = sv[bl * 64 + quad * 16 + col];
        f32x4 c0 = {0.0f, 0.0f, 0.0f, 0.0f};
        const f32x4 dd = __builtin_amdgcn_mfma_f32_16x16x32_f16(A.v, B.h, c0, 0, 0, 0);
        const float aj = sa[bl * 16 + col];
#pragma unroll
        for (int r2 = 0; r2 < 4; ++r2) {
            const float K = __builtin_amdgcn_exp2f(dd[r2]);
            R2[r2] += K;
            Q2[r2] = fmaf(aj, K, Q2[r2]);
        }
    }
    // Peeled weight-1 iterations (block-uniform branches).
    if (dc == NDC - 1 || dc == 0) {
        const int bl = (dc == 0) ? wave : wave + 32;   // d=0 diag / d=288
        union { uint4 q; half8 h; } B;
        B.q = sv[bl * 64 + quad * 16 + col];
        f32x4 c0 = {0.0f, 0.0f, 0.0f, 0.0f};
        const f32x4 dd = __builtin_amdgcn_mfma_f32_16x16x32_f16(A.v, B.h, c0, 0, 0, 0);
        const float aj = sa[bl * 16 + col];
#pragma unroll
        for (int r2 = 0; r2 < 4; ++r2) {
            const float K = __builtin_amdgcn_exp2f(dd[r2]);
            R1[r2] += K;
            Q1[r2] = fmaf(aj, K, Q1[r2]);
        }
    }

    // Apply per-row factors: sum w*K*(ai + aj*(1-2ai)) = ai*R + (1-2ai)*Q.
    float s4 = 0.0f;
#pragma unroll
    for (int r2 = 0; r2 < 4; ++r2) {
        const float Rt = fmaf(2.0f, R2[r2], R1[r2]);
        const float Qt = fmaf(2.0f, Q2[r2], Q1[r2]);
        const float ci = fmaf(-2.0f, air[r2], 1.0f);
        s4 += fmaf(air[r2], Rt, ci * Qt);
    }
    for (int off = 32; off > 0; off >>= 1)
        s4 += __shfl_down(s4, off, 64);
    if (lane == 0) wsum[wave] = s4;
    __syncthreads();
    if (tid == 0) {
        float bs = 0.0f;
#pragma unroll
        for (int w = 0; w < 8; ++w) bs += wsum[w];
        partials[dc * AG + g] = bs;
    }
}

__global__ __launch_bounds__(256) void crf_finalize_kernel(
    const float* __restrict__ partials, float* __restrict__ out)
{
    const int tid = threadIdx.x;
    float s = 0.0f;
    for (int t = tid; t < NPART; t += 256)
        s += partials[t];
    for (int off = 32; off > 0; off >>= 1)
        s += __shfl_down(s, off, 64);
    __shared__ float wsum[4];
    if ((tid & 63) == 0) wsum[tid >> 6] = s;
    __syncthreads();
    if (tid == 0)
        out[0] = ((wsum[0] + wsum[1]) + (wsum[2] + wsum[3])) * (1.0f / (float)NN);
}

extern "C" void kernel_launch(void* const* d_in, const int* in_sizes, int n_in,
                              void* d_out, int out_size, void* d_ws, size_t ws_size,
                              hipStream_t stream) {
    const float* probs = (const float*)d_in[0];  // [1,2,96,96] fp32
    const float* image = (const float*)d_in[1];  // [1,3,96,96] fp32
    float* out = (float*)d_out;                  // [1] fp32
    float* partials = (float*)d_ws;              // NPART floats

    crf_mfma3<<<dim3(AG, NDC), dim3(BLK), 0, stream>>>(probs, image, partials);
    crf_finalize_kernel<<<dim3(1), dim3(256), 0, stream>>>(partials, out);
}